// Round 11
// baseline (117.969 us; speedup 1.0000x reference)
//
#include <hip/hip_runtime.h>
#include <hip/hip_bf16.h>

#define BS 4
#define NF 8
#define NT 256
#define DIN 64
#define NH 8
#define DOUT 64
#define TT 4          // t's per attn block
#define MROWS 32      // TT*NH score rows per block
#define NCH 64        // NT/TT

typedef unsigned short u16;
typedef __attribute__((ext_vector_type(8))) short short8;
typedef __attribute__((ext_vector_type(4))) float f32x4;
typedef __attribute__((ext_vector_type(4))) unsigned int u32x4;

static __device__ __forceinline__ u16 f2bf(float x) {
    __hip_bfloat16 h = __float2bfloat16(x);
    u16 r; __builtin_memcpy(&r, &h, 2); return r;
}
static __device__ __forceinline__ unsigned pk2(float a, float b) {
    return (unsigned)f2bf(a) | ((unsigned)f2bf(b) << 16);
}

// ---------------------------------------------------------------------------
// prep (UNCHANGED from round 10): [0,2048) qk projection, block per (f,t);
//   Wq/Wk staged transposed in LDS, b128 compute reads; q/k normal layout.
//   [2048,2176) X -> XT bf16 [bf][d][l] ; [2176,2240) W -> Wt bf16 [f][o][kk]
// ---------------------------------------------------------------------------
__global__ __launch_bounds__(256) void prep_kernel(
    const float* __restrict__ X,
    const float* __restrict__ Wq,
    const float* __restrict__ Wk,
    const float* __restrict__ W,
    float* __restrict__ q,
    float* __restrict__ k,
    u16* __restrict__ XT,
    u16* __restrict__ Wt)
{
    __shared__ float sm[4160];          // union: qk {sWt[2176], sX[256]} | sT[64][65]
    const int tid = threadIdx.x;
    const int bid = blockIdx.x;

    if (bid < 2048) {
        const int ft = bid;             // f*NT + t
        const int f = ft >> 8, t = ft & 255;
        float* sWt = sm;                // [which*1088 + he*68 + d]
        float* sX  = sm + 2176;         // [b*64 + d]

        float4 a4 = ((const float4*)(Wq + ((size_t)ft << 10)))[tid];
        float4 b4 = ((const float4*)(Wk + ((size_t)ft << 10)))[tid];
        {
            int d = tid >> 2, he = (tid & 3) << 2;
            sWt[(he + 0) * 68 + d] = a4.x;
            sWt[(he + 1) * 68 + d] = a4.y;
            sWt[(he + 2) * 68 + d] = a4.z;
            sWt[(he + 3) * 68 + d] = a4.w;
            sWt[1088 + (he + 0) * 68 + d] = b4.x;
            sWt[1088 + (he + 1) * 68 + d] = b4.y;
            sWt[1088 + (he + 2) * 68 + d] = b4.z;
            sWt[1088 + (he + 3) * 68 + d] = b4.w;
            int xb = tid >> 6, xd = tid & 63;
            sX[tid] = X[(((size_t)((xb * NF + f) * NT + t)) << 6) + xd];
        }
        __syncthreads();

        const int half  = tid & 1;
        const int he    = (tid >> 1) & 15;
        const int b     = (tid >> 5) & 3;
        const int which = tid >> 7;
        const float* wp = sWt + which * 1088 + he * 68 + (half << 5);
        const float* xp = sX + (b << 6) + (half << 5);
        float acc = 0.f;
        #pragma unroll
        for (int j = 0; j < 8; ++j) {
            float4 w = *(const float4*)(wp + (j << 2));
            float4 x = *(const float4*)(xp + (j << 2));
            acc = fmaf(w.x, x.x, acc);
            acc = fmaf(w.y, x.y, acc);
            acc = fmaf(w.z, x.z, acc);
            acc = fmaf(w.w, x.w, acc);
        }
        acc += __shfl_xor(acc, 1);
        if (half == 0) {
            float* outp = which ? k : q;
            outp[(((size_t)((b * NF + f) * NT + t)) << 4) + he] = acc;
        }
    } else if (bid < 2176) {
        const int idx = bid - 2048;     // (bf, lc)
        const int bf = idx >> 2, lc = idx & 3;
        float (*sT)[65] = (float(*)[65])sm;
        #pragma unroll
        for (int i = 0; i < 16; ++i) {
            int l = i * 4 + (tid >> 6), d = tid & 63;
            sT[l][d] = X[(((size_t)(bf * NT) + lc * 64 + l) << 6) + d];
        }
        __syncthreads();
        #pragma unroll
        for (int i = 0; i < 16; ++i) {
            int d = i * 4 + (tid >> 6), l = tid & 63;
            XT[(((size_t)(bf * 64) + d) << 8) + lc * 64 + l] = f2bf(sT[l][d]);
        }
    } else {
        const int idx = bid - 2176;
        const int f = idx >> 3, kc = idx & 7;
        float (*sT)[65] = (float(*)[65])sm;
        #pragma unroll
        for (int i = 0; i < 16; ++i) {
            int kk = i * 4 + (tid >> 6), o = tid & 63;
            sT[kk][o] = W[(((size_t)(f * 512) + kc * 64 + kk) << 6) + o];
        }
        __syncthreads();
        #pragma unroll
        for (int i = 0; i < 16; ++i) {
            int o = i * 4 + (tid >> 6), kk = tid & 63;
            Wt[(((size_t)(f * 64) + o) << 9) + kc * 64 + kk] = f2bf(sT[kk][o]);
        }
    }
}

// ---------------------------------------------------------------------------
// attn v11 = R10 (overlay) + latency attack:
//   phase-3 XT prefetch 2-deep, phase-4 Wt prefetch 3-deep,
//   bias prefetched at kernel top. Math/layout identical to R10.
// ---------------------------------------------------------------------------
__global__ __launch_bounds__(256, 4) void attn_kernel(
    const float* __restrict__ ac,
    const float* __restrict__ alpha,
    const float* __restrict__ Wkey_,
    const float* __restrict__ u,
    const float* __restrict__ bias,
    const float* __restrict__ q,
    const float* __restrict__ kws,
    const u16* __restrict__ XT,
    const u16* __restrict__ Wt,
    float* __restrict__ out)
{
    __shared__ __align__(16) u16 sU16[9216];  // 18 KB union: sKU fp32[4608] | sP[32][256] | sVals[16][520]
    __shared__ float sRed[MROWS * 16];        // 2 KB, [m][lg]
    __shared__ float sM[MROWS];
    __shared__ float sInvS[MROWS];

    float* sKU = (float*)sU16;

    const int tid = threadIdx.x;
    const int bid = blockIdx.x;
    const int ch = bid & 63;
    const int f  = (bid >> 6) & 7;
    const int b  = bid >> 9;
    const int bf = b * NF + f;
    const int t0 = ch * TT;

    const int wv   = tid >> 6;
    const int lane = tid & 63;
    const int quad = lane >> 4;
    const int ln   = lane & 15;
    const int mh   = wv & 1;          // m-half for phase 3
    const int nh   = wv >> 1;         // n-half for phase 3

    // ---- bias prefetch (epilogue operands; latency drains behind staging) --
    float bpre[4] = {0.f, 0.f, 0.f, 0.f};
    if (quad == 0) {
        int o = wv * 16 + ln;
        #pragma unroll
        for (int reg = 0; reg < 4; ++reg)
            bpre[reg] = bias[((size_t)((f << 8) + t0 + reg) << 6) + o];
    }

    // ---- stage K (fp32) and U ----
    {
        const float4* k4 = (const float4*)(kws + ((size_t)bf << 12));
        float4* d4 = (float4*)sKU;
        #pragma unroll
        for (int i = 0; i < 4; ++i) d4[i * 256 + tid] = k4[i * 256 + tid];
        if (tid < 128) ((float4*)(sKU + 4096))[tid] = ((const float4*)(u + f * 512))[tid];
    }
    __syncthreads();

    const int h  = tid & 7;
    const int tp = (tid >> 3) & 1;
    const int lg = tid >> 4;          // 0..15
    const int t_a = t0 + tp * 2, t_b = t_a + 1;
    const int m_a = tp * 16 + h, m_b = m_a + 8;   // m_a&15 = h, m_b&15 = h+8
    const int lbase = lg * 16;

    // ---- per-row constants (registers, 2 rows per thread) ----
    float q0a, q1a, kt0a, kt1a, c2a, c1a;
    float q0b, q1b, kt0b, kt1b, c2b, c1b;
    {
        float al = alpha[f];
        float acv = ac[f * 8 + h];
        float wk0 = Wkey_[f * 4],     wk1 = Wkey_[f * 4 + 1];
        float wk2 = Wkey_[f * 4 + 2], wk3 = Wkey_[f * 4 + 3];
        float2 qa = *(const float2*)(q + ((size_t)(bf * NT + t_a) << 4) + (h << 1));
        float2 qb = *(const float2*)(q + ((size_t)(bf * NT + t_b) << 4) + (h << 1));
        q0a = qa.x; q1a = qa.y; q0b = qb.x; q1b = qb.y;
        kt0a = sKU[t_a * 16 + h * 2]; kt1a = sKU[t_a * 16 + h * 2 + 1];
        kt0b = sKU[t_b * 16 + h * 2]; kt1b = sKU[t_b * 16 + h * 2 + 1];
        float a0 = q0a - al, a1 = q1a + 2.f * al * acv;
        c2a = a0 * wk0 + a1 * wk2; c1a = a0 * wk1 + a1 * wk3;
        a0 = q0b - al; a1 = q1b + 2.f * al * acv;
        c2b = a0 * wk0 + a1 * wk2; c1b = a0 * wk1 + a1 * wk3;
    }

    // ---- pass A: scores into registers + running max (K/U from LDS) ----
    float sA[16], sB[16];
    float mxa = -1e30f, mxb = -1e30f;
    {
        float rela = (float)(lbase - t_a);
        #pragma unroll
        for (int j = 0; j < 16; ++j) {
            int l = lbase + j;
            float2 K = *(const float2*)(sKU + l * 16 + h * 2);
            float2 U = *(const float2*)(sKU + 4096 + l * 2);
            float relb = rela - 1.f;
            float sa = (c2a * rela + c1a) * rela;
            sa = fmaf(q0a, K.x, sa); sa = fmaf(q1a, K.y, sa);
            sa = fmaf(kt0a, U.x, sa); sa = fmaf(kt1a, U.y, sa);
            float sb = (c2b * relb + c1b) * relb;
            sb = fmaf(q0b, K.x, sb); sb = fmaf(q1b, K.y, sb);
            sb = fmaf(kt0b, U.x, sb); sb = fmaf(kt1b, U.y, sb);
            sA[j] = sa; sB[j] = sb;
            mxa = fmaxf(mxa, sa); mxb = fmaxf(mxb, sb);
            rela += 1.f;
        }
    }
    sRed[m_a * 16 + lg] = mxa;
    sRed[m_b * 16 + lg] = mxb;
    __syncthreads();                         // last sKU read is above
    if (tid < MROWS) {
        const float4* r4 = (const float4*)(sRed + tid * 16);
        float4 r0 = r4[0], r1 = r4[1], r2 = r4[2], r3 = r4[3];
        float mm = fmaxf(fmaxf(fmaxf(r0.x, r0.y), fmaxf(r0.z, r0.w)),
                         fmaxf(fmaxf(r1.x, r1.y), fmaxf(r1.z, r1.w)));
        mm = fmaxf(mm, fmaxf(fmaxf(fmaxf(r2.x, r2.y), fmaxf(r2.z, r2.w)),
                             fmaxf(fmaxf(r3.x, r3.y), fmaxf(r3.z, r3.w))));
        sM[tid] = mm;
    }
    __syncthreads();

    // ---- pass B: exp from regs, sums, P writes (OVERLAYS sKU - now dead) --
    u16* sP = sU16;
    {
        const float Ma = sM[m_a], Mb = sM[m_b];
        float suma = 0.f, sumb = 0.f;
        unsigned pka[4], pkb[4];
        float epa = 0.f, epb = 0.f;
        #pragma unroll
        for (int j = 0; j < 16; ++j) {
            float ea = __expf(sA[j] - Ma), eb = __expf(sB[j] - Mb);
            suma += ea; sumb += eb;
            if ((j & 1) == 0) { epa = ea; epb = eb; }
            else { pka[(j & 7) >> 1] = pk2(epa, ea); pkb[(j & 7) >> 1] = pk2(epb, eb); }
            if ((j & 7) == 7) {
                int chunk = lg * 2 + (j >> 3);
                int pa = chunk ^ h;
                int pb = chunk ^ (h + 8);
                *(u32x4*)&sP[m_a * 256 + pa * 8] = (u32x4){pka[0], pka[1], pka[2], pka[3]};
                *(u32x4*)&sP[m_b * 256 + pb * 8] = (u32x4){pkb[0], pkb[1], pkb[2], pkb[3]};
            }
        }
        sRed[m_a * 16 + lg] = suma;
        sRed[m_b * 16 + lg] = sumb;
    }

    // ---- prefetch XT ks=0,1 b-frags (2-deep) across the reduction barrier --
    const u16* xb = XT + ((size_t)bf << 14);
    short8 pb0[2], pb1[2];
    {
        int l2 = quad * 8;
        pb0[0] = *(const short8*)(xb + (nh * 32 + ln) * 256 + l2);
        pb1[0] = *(const short8*)(xb + (nh * 32 + 16 + ln) * 256 + l2);
        pb0[1] = *(const short8*)(xb + (nh * 32 + ln) * 256 + 32 + l2);
        pb1[1] = *(const short8*)(xb + (nh * 32 + 16 + ln) * 256 + 32 + l2);
    }
    __syncthreads();
    if (tid < MROWS) {
        const float4* r4 = (const float4*)(sRed + tid * 16);
        float4 r0 = r4[0], r1 = r4[1], r2 = r4[2], r3 = r4[3];
        float ss = ((r0.x + r0.y) + (r0.z + r0.w)) + ((r1.x + r1.y) + (r1.z + r1.w))
                 + ((r2.x + r2.y) + (r2.z + r2.w)) + ((r3.x + r3.y) + (r3.z + r3.w));
        sInvS[tid] = 1.f / ss;
    }
    __syncthreads();

    // ---- phase 3: vals = P @ X via 2-deep pipelined MFMA (M=32,K=256,N=64) -
    f32x4 acc0 = {0.f, 0.f, 0.f, 0.f}, acc1 = acc0;
    #pragma unroll
    for (int ks = 0; ks < 8; ++ks) {
        short8 b0 = pb0[ks & 1], b1 = pb1[ks & 1];
        if (ks < 6) {
            int l2 = (ks + 2) * 32 + quad * 8;
            pb0[ks & 1] = *(const short8*)(xb + (nh * 32 + ln) * 256 + l2);
            pb1[ks & 1] = *(const short8*)(xb + (nh * 32 + 16 + ln) * 256 + l2);
        }
        int phys = (ks * 4 + quad) ^ ln;
        short8 a = *(const short8*)&sP[(mh * 16 + ln) * 256 + phys * 8];
        acc0 = __builtin_amdgcn_mfma_f32_16x16x32_bf16(a, b0, acc0, 0, 0, 0);
        acc1 = __builtin_amdgcn_mfma_f32_16x16x32_bf16(a, b1, acc1, 0, 0, 0);
    }
    float inv0 = sInvS[mh * 16 + quad * 4 + 0];
    float inv1 = sInvS[mh * 16 + quad * 4 + 1];
    float inv2 = sInvS[mh * 16 + quad * 4 + 2];
    float inv3 = sInvS[mh * 16 + quad * 4 + 3];
    // ---- prefetch Wt ks=0..2 (3-deep) before the sVals barriers ----
    const u16* wb = Wt + ((size_t)(f * 64 + wv * 16 + ln) << 9);
    short8 wp3[3];
    wp3[0] = *(const short8*)(wb + 0 * 32 + quad * 8);
    wp3[1] = *(const short8*)(wb + 1 * 32 + quad * 8);
    wp3[2] = *(const short8*)(wb + 2 * 32 + quad * 8);
    __syncthreads();                         // all sP reads complete

    // ---- sVals (overlays the same region) ----
    u16* sVals = sU16;   // [tl][520]
    {
        float invs[4] = {inv0, inv1, inv2, inv3};
        #pragma unroll
        for (int reg = 0; reg < 4; ++reg) {
            int mg = mh * 16 + quad * 4 + reg;
            int tl = mg >> 3, hh = mg & 7;
            u16* dst = sVals + tl * 520 + hh * 64 + nh * 32 + ln;
            dst[0]  = f2bf(acc0[reg] * invs[reg]);
            dst[16] = f2bf(acc1[reg] * invs[reg]);
        }
    }
    __syncthreads();

    // ---- phase 4: out = vals @ W via 3-deep pipelined MFMA (M=4(16),K=512) -
    f32x4 oacc = {0.f, 0.f, 0.f, 0.f};
    #pragma unroll
    for (int ks = 0; ks < 16; ++ks) {
        short8 bw = wp3[ks % 3];
        if (ks < 13) wp3[ks % 3] = *(const short8*)(wb + (ks + 3) * 32 + quad * 8);
        short8 a = *(const short8*)(sVals + ln * 520 + ks * 32 + quad * 8);
        oacc = __builtin_amdgcn_mfma_f32_16x16x32_bf16(a, bw, oacc, 0, 0, 0);
    }
    {
        int o = wv * 16 + ln;
        #pragma unroll
        for (int reg = 0; reg < 4; ++reg) {
            int tl = quad * 4 + reg;
            if (tl < TT) {
                int tg = t0 + tl;
                out[((size_t)(bf * NT + tg) << 6) + o] = oacc[reg] + bpre[reg];
            }
        }
    }
}

extern "C" void kernel_launch(void* const* d_in, const int* in_sizes, int n_in,
                              void* d_out, int out_size, void* d_ws, size_t ws_size,
                              hipStream_t stream) {
    const float* X     = (const float*)d_in[0];
    const float* ac    = (const float*)d_in[1];
    const float* alpha = (const float*)d_in[2];
    const float* Wq    = (const float*)d_in[3];
    const float* Wk    = (const float*)d_in[4];
    const float* Wkey_ = (const float*)d_in[5];
    const float* u     = (const float*)d_in[6];
    const float* W     = (const float*)d_in[7];
    const float* bb    = (const float*)d_in[8];
    float* out = (float*)d_out;

    float* qws = (float*)d_ws;                  // 131072 f
    float* kws = qws + 131072;                  // 131072 f
    u16* XT = (u16*)(kws + 131072);             // 524288 u16
    u16* Wt = XT + 524288;                      // 262144 u16

    hipLaunchKernelGGL(prep_kernel, dim3(2240), dim3(256), 0, stream,
                       X, Wq, Wk, W, qws, kws, XT, Wt);
    hipLaunchKernelGGL(attn_kernel, dim3(BS * NF * NCH), dim3(256), 0, stream,
                       ac, alpha, Wkey_, u, bb, qws, kws, XT, Wt, out);
}